// Round 5
// baseline (159.303 us; speedup 1.0000x reference)
//
#include <hip/hip_runtime.h>

// Lucas-Kanade optical flow v5.
// - RB=4 rows/block, 4608 one-wave blocks, XCD-chunked band swizzle.
// - rows[19] register pipeline: entering rows prefetched 2-3 steps ahead;
//   exiting window rows are rows[0..3], kept live -> zero exit reloads.
// - One fast path for all strips: per-lane predicated float4 loads,
//   col-4 terms via lazy shuffle with keep4/rep4 edge fixups.
// Derivatives unscaled (8fx, 8fy, 4ft); exact power-of-2 rescale (x2) folded
// into the final u,v.

constexpr int IH  = 2048;
constexpr int IW  = 2048;
constexpr int RAD = 7;
constexpr int WIN = 15;
constexpr int NT  = 64;              // 1 wave per block
constexpr int SW  = 240;             // output columns per block (lanes 0..59 store)
constexpr int RB  = 4;               // output rows per block
constexpr int SCAN  = RB + WIN - 1;  // 18 scan steps
constexpr int NROWS = SCAN + 1;      // 19 source rows: r0-7 .. r0+11
constexpr int NSTRIP = 9;
constexpr int NBAND  = IH / RB;      // 512
constexpr int NXCD   = 8;
constexpr int CHUNK  = NBAND / NXCD; // 64 bands per XCD per strip

// Per-row derived terms for this lane's 4 columns: sp = prev+next, dt = next-prev.
struct Row { float sp[4]; float dt[4]; };

template<bool YE>
__device__ __forceinline__ Row load_row(const float* __restrict__ P,
                                        const float* __restrict__ N,
                                        int row, int pcb, bool lload) {
    if constexpr (YE) row = row < 0 ? 0 : (row > IH - 1 ? IH - 1 : row);
    float4 q = make_float4(0.f, 0.f, 0.f, 0.f);
    float4 r = q;
    if (lload) {   // uniform-true for interior strips; masks OOB lanes on edges
        const size_t off = (size_t)row * IW + pcb;
        q = *reinterpret_cast<const float4*>(P + off);   // 16B aligned
        r = *reinterpret_cast<const float4*>(N + off);
    }
    Row R;
    R.sp[0] = q.x + r.x; R.dt[0] = r.x - q.x;
    R.sp[1] = q.y + r.y; R.dt[1] = r.y - q.y;
    R.sp[2] = q.z + r.z; R.dt[2] = r.z - q.z;
    R.sp[3] = q.w + r.w; R.dt[3] = r.w - q.w;
    return R;
}

// Add (SUB=false) or remove (SUB=true) product row pair (A=row r, B=row r+1).
template<bool SUB, bool XE>
__device__ __forceinline__ void accum(float V[5][4], const Row& A, const Row& B,
                                      int t, float keep4, bool rep4) {
    float g[5], m[5], e[5];
    #pragma unroll
    for (int c = 0; c < 4; ++c) {
        g[c] = A.sp[c] + B.sp[c];   // -> 8*fx via horizontal diff
        m[c] = B.sp[c] - A.sp[c];   // -> 8*fy
        e[c] = A.dt[c] + B.dt[c];   // -> 4*ft
    }
    // col-4 terms = neighbor lane's col 0 (lane 63's value feeds only the
    // untracked product col; never read by a storing lane).
    float g4 = __shfl(g[0], t + 1);
    float m4 = __shfl(m[0], t + 1);
    float e4 = __shfl(e[0], t + 1);
    if constexpr (XE) {
        g4 = (rep4 ? g[3] : g4) * keep4;   // right edge: replicate last col
        m4 = (rep4 ? m[3] : m4) * keep4;   // left edge: zero (outside image)
        e4 = (rep4 ? e[3] : e4) * keep4;
    }
    g[4] = g4; m[4] = m4; e[4] = e4;
    #pragma unroll
    for (int c = 0; c < 4; ++c) {
        const float fx = g[c + 1] - g[c];
        const float fy = m[c] + m[c + 1];
        const float ft = e[c] + e[c + 1];
        if (!SUB) {
            V[0][c] += fx * fx; V[1][c] += fx * fy; V[2][c] += fy * fy;
            V[3][c] += fx * ft; V[4][c] += fy * ft;
        } else {
            V[0][c] -= fx * fx; V[1][c] -= fx * fy; V[2][c] -= fy * fy;
            V[3][c] -= fx * ft; V[4][c] -= fy * ft;
        }
    }
}

template<bool XE, bool YE>
__device__ __forceinline__ void lk_body(const float* __restrict__ P,
                                        const float* __restrict__ N,
                                        float* __restrict__ out,
                                        int c0, int r0, int t) {
    const int ci0 = 4 * t;
    const int pcb = c0 - 8 + ci0;       // this lane's first tracked column
    bool  lload = true;
    float keep4 = 1.f;
    bool  rep4  = false;
    if constexpr (XE) {
        lload = (pcb >= 0) && (pcb + 3 < IW);  // full float4 in range
        keep4 = (pcb + 3 >= 0) ? 1.f : 0.f;    // col pcb+3 outside-left -> zero
        rep4  = (pcb + 4 >= IW);               // col pcb+4 outside-right -> replicate
    }

    Row rows[NROWS];                    // rows[k] = image row r0-7+k
    rows[0] = load_row<YE>(P, N, r0 - RAD + 0, pcb, lload);
    rows[1] = load_row<YE>(P, N, r0 - RAD + 1, pcb, lload);
    rows[2] = load_row<YE>(P, N, r0 - RAD + 2, pcb, lload);

    float V[5][4] = {};

    #pragma unroll
    for (int sr = 0; sr < SCAN; ++sr) {
        const int pr = r0 - RAD + sr;   // entering product row

        // prefetch row pr+3 (used at step sr+2 / sr+3)
        if (sr + 3 < NROWS)
            rows[sr + 3] = load_row<YE>(P, N, pr + 3, pcb, lload);

        bool enter_ok = true;
        bool exit_ok  = (sr >= WIN);
        if constexpr (YE) {
            enter_ok = (pr >= 0) && (pr < IH);
            exit_ok  = exit_ok && (pr - WIN >= 0);
        }
        if (enter_ok)
            accum<false, XE>(V, rows[sr], rows[sr + 1], t, keep4, rep4);
        if (exit_ok)                     // exit rows are rows[0..3] (kept live)
            accum<true, XE>(V, rows[sr - WIN], rows[sr - WIN + 1], t, keep4, rep4);

        if (sr >= WIN - 1) {
            // horizontal 15-tap via shuffles, 4 outputs per thread
            float a[5][4];
            #pragma unroll
            for (int p = 0; p < 5; ++p) {
                const float v0 = V[p][0], v1 = V[p][1], v2 = V[p][2], v3 = V[p][3];
                const float Pg = (v0 + v1) + (v2 + v3);
                const float S1 = __shfl(Pg, t + 1);
                const float S2 = __shfl(Pg, t + 2);
                const float S3 = __shfl(Pg, t + 3);
                const float q0 = __shfl(v0, t + 4);
                const float q1 = __shfl(v1, t + 4);
                const float q2 = __shfl(v2, t + 4);
                a[p][0] = ((Pg - v0) + S1) + (S2 + S3);
                a[p][1] = a[p][0] - v1 + q0;
                a[p][2] = a[p][1] - v2 + q1;
                a[p][3] = a[p][2] - v3 + q2;
            }
            const int i = pr - RAD;     // output row in [r0, r0+RB)
            const int x = c0 + ci0;
            if (ci0 < SW && x < IW) {
                float4 qu, qv;
                float* uo = &qu.x; float* vo = &qv.x;
                #pragma unroll
                for (int c = 0; c < 4; ++c) {
                    const float Axx = a[0][c], Axy = a[1][c], Ayy = a[2][c];
                    const float bx = a[3][c], by = a[4][c];
                    const float det = Axx * Ayy - Axy * Axy;
                    const float rd  = __builtin_amdgcn_rcpf(det) * 2.0f;  // fold scale
                    const bool  ok  = (det != 0.f);
                    uo[c] = ok ? (Ayy * bx - Axy * by) * rd : 0.f;
                    vo[c] = ok ? (Axx * by - Axy * bx) * rd : 0.f;
                }
                *reinterpret_cast<float4*>(out + (size_t)i * IW + x) = qu;
                *reinterpret_cast<float4*>(out + (size_t)IH * IW + (size_t)i * IW + x) = qv;
            }
        }
    }
}

__global__ __launch_bounds__(NT, 4)
void lk_kernel(const float* __restrict__ Pimg, const float* __restrict__ Nimg,
               float* __restrict__ out) {
    // XCD-chunked swizzle: XCD (bid&7) owns 64 contiguous 4-row bands of one
    // strip, so vertical-halo re-reads across adjacent bands hit the local L2.
    const int bid   = blockIdx.x;
    const int xcd   = bid & 7;
    const int idx   = bid >> 3;              // 0..575
    const int strip = idx / CHUNK;           // 0..8
    const int pos   = idx % CHUNK;
    const int band  = xcd * CHUNK + pos;     // 0..511
    const int c0 = strip * SW;
    const int r0 = band * RB;
    const int t  = threadIdx.x;
    const bool xe = (strip == 0) || (strip == NSTRIP - 1);
    const bool ye = (band < 2) || (band > NBAND - 3);
    if (!xe && !ye)      lk_body<false, false>(Pimg, Nimg, out, c0, r0, t);
    else if (xe && !ye)  lk_body<true,  false>(Pimg, Nimg, out, c0, r0, t);
    else if (!xe)        lk_body<false, true >(Pimg, Nimg, out, c0, r0, t);
    else                 lk_body<true,  true >(Pimg, Nimg, out, c0, r0, t);
}

extern "C" void kernel_launch(void* const* d_in, const int* in_sizes, int n_in,
                              void* d_out, int out_size, void* d_ws, size_t ws_size,
                              hipStream_t stream) {
    (void)in_sizes; (void)n_in; (void)d_ws; (void)ws_size; (void)out_size;
    const float* prev = (const float*)d_in[0];
    const float* nxt  = (const float*)d_in[1];
    float* out        = (float*)d_out;
    dim3 grid(NSTRIP * NBAND);               // 4608 one-wave blocks
    dim3 block(NT);
    hipLaunchKernelGGL(lk_kernel, grid, block, 0, stream, prev, nxt, out);
}

// Round 6
// 78.099 us; speedup vs baseline: 2.0397x; 2.0397x over previous
//
#include <hip/hip_runtime.h>

// Lucas-Kanade optical flow v6.
// Spill-free redesign of v5: only 8 Rows live (pinned exit rows X0..X3 +
// sliding A,B,C,D with 3-step prefetch distance), step loop fully static via
// recursive template<int SR> (no runtime-indexed arrays -> nothing can fall
// to scratch). RB=4, 4608 one-wave blocks, XCD-chunked band swizzle, single
// predicated-float4 path for all strips.
// Derivatives unscaled (8fx, 8fy, 4ft); exact power-of-2 rescale (x2) folded
// into the final u,v.

constexpr int IH  = 2048;
constexpr int IW  = 2048;
constexpr int RAD = 7;
constexpr int WIN = 15;
constexpr int NT  = 64;              // 1 wave per block
constexpr int SW  = 240;             // output columns per block (lanes 0..59 store)
constexpr int RB  = 4;               // output rows per block
constexpr int SCAN  = RB + WIN - 1;  // 18 steps; source rows r0-7 .. r0+11
constexpr int NSTRIP = 9;
constexpr int NBAND  = IH / RB;      // 512
constexpr int NXCD   = 8;
constexpr int CHUNK  = NBAND / NXCD; // 64 bands per XCD per strip

// Per-row derived terms for this lane's 4 columns: sp = prev+next, dt = next-prev.
struct Row { float sp[4]; float dt[4]; };

template<bool YE>
__device__ __forceinline__ Row load_row(const float* __restrict__ P,
                                        const float* __restrict__ N,
                                        int row, int pcb, bool lload) {
    if constexpr (YE) row = row < 0 ? 0 : (row > IH - 1 ? IH - 1 : row);
    float4 q = make_float4(0.f, 0.f, 0.f, 0.f);
    float4 r = q;
    if (lload) {   // uniform-true for interior strips; masks OOB lanes on edges
        const size_t off = (size_t)row * IW + pcb;
        q = *reinterpret_cast<const float4*>(P + off);   // 16B aligned
        r = *reinterpret_cast<const float4*>(N + off);
    }
    Row R;
    R.sp[0] = q.x + r.x; R.dt[0] = r.x - q.x;
    R.sp[1] = q.y + r.y; R.dt[1] = r.y - q.y;
    R.sp[2] = q.z + r.z; R.dt[2] = r.z - q.z;
    R.sp[3] = q.w + r.w; R.dt[3] = r.w - q.w;
    return R;
}

// Add (SUB=false) or remove (SUB=true) product-row pair (A=row r, B=row r+1).
template<bool SUB, bool XE>
__device__ __forceinline__ void accum(float V[5][4], const Row& A, const Row& B,
                                      int t, float keep4, bool rep4) {
    float g[5], m[5], e[5];
    #pragma unroll
    for (int c = 0; c < 4; ++c) {
        g[c] = A.sp[c] + B.sp[c];   // -> 8*fx via horizontal diff
        m[c] = B.sp[c] - A.sp[c];   // -> 8*fy
        e[c] = A.dt[c] + B.dt[c];   // -> 4*ft
    }
    // col-4 terms = neighbor lane's col 0 (lane 63's wrap feeds only the
    // untracked product col; never read by a storing lane).
    float g4 = __shfl(g[0], t + 1);
    float m4 = __shfl(m[0], t + 1);
    float e4 = __shfl(e[0], t + 1);
    if constexpr (XE) {
        g4 = (rep4 ? g[3] : g4) * keep4;   // right edge: replicate; left: zero
        m4 = (rep4 ? m[3] : m4) * keep4;
        e4 = (rep4 ? e[3] : e4) * keep4;
    }
    g[4] = g4; m[4] = m4; e[4] = e4;
    #pragma unroll
    for (int c = 0; c < 4; ++c) {
        const float fx = g[c + 1] - g[c];
        const float fy = m[c] + m[c + 1];
        const float ft = e[c] + e[c + 1];
        if (!SUB) {
            V[0][c] += fx * fx; V[1][c] += fx * fy; V[2][c] += fy * fy;
            V[3][c] += fx * ft; V[4][c] += fy * ft;
        } else {
            V[0][c] -= fx * fx; V[1][c] -= fx * fy; V[2][c] -= fy * fy;
            V[3][c] -= fx * ft; V[4][c] -= fy * ft;
        }
    }
}

template<int SR, bool XE, bool YE>
__device__ __forceinline__ void lk_step(const float* __restrict__ P,
                                        const float* __restrict__ N,
                                        float* __restrict__ out,
                                        int c0, int r0, int t, int pcb,
                                        bool lload, float keep4, bool rep4,
                                        Row& A, Row& B, Row& C, Row& D,
                                        const Row& X0, const Row& X1,
                                        const Row& X2, const Row& X3,
                                        float V[5][4]) {
    const int pr = r0 - RAD + SR;       // entering product row

    // prefetch rows[SR+4] = image row pr+4 (used as B three steps from now)
    Row nD;
    if constexpr (SR + 4 <= SCAN)
        nD = load_row<YE>(P, N, pr + 4, pcb, lload);

    // entering product row pair (A=rows[SR], B=rows[SR+1])
    bool enter_ok = true;
    if constexpr (YE) enter_ok = (pr >= 0) && (pr < IH);
    if (enter_ok) accum<false, XE>(V, A, B, t, keep4, rep4);

    // exiting product row pair: rows[SR-15], rows[SR-14] == pinned X's
    if constexpr (SR >= WIN) {
        bool exit_ok = true;
        if constexpr (YE) exit_ok = (pr - WIN) >= 0;
        if (exit_ok) {
            if constexpr (SR == 15) accum<true, XE>(V, X0, X1, t, keep4, rep4);
            if constexpr (SR == 16) accum<true, XE>(V, X1, X2, t, keep4, rep4);
            if constexpr (SR == 17) accum<true, XE>(V, X2, X3, t, keep4, rep4);
        }
    }

    // emit output row i = r0 + SR-14
    if constexpr (SR >= WIN - 1) {
        float a[5][4];
        #pragma unroll
        for (int p = 0; p < 5; ++p) {
            const float v0 = V[p][0], v1 = V[p][1], v2 = V[p][2], v3 = V[p][3];
            const float Pg = (v0 + v1) + (v2 + v3);
            const float S1 = __shfl(Pg, t + 1);
            const float S2 = __shfl(Pg, t + 2);
            const float S3 = __shfl(Pg, t + 3);
            const float q0 = __shfl(v0, t + 4);
            const float q1 = __shfl(v1, t + 4);
            const float q2 = __shfl(v2, t + 4);
            a[p][0] = ((Pg - v0) + S1) + (S2 + S3);
            a[p][1] = a[p][0] - v1 + q0;
            a[p][2] = a[p][1] - v2 + q1;
            a[p][3] = a[p][2] - v3 + q2;
        }
        const int i = r0 + (SR - (WIN - 1));
        const int x = c0 + 4 * t;
        if (4 * t < SW && x < IW) {
            float4 qu, qv;
            float* uo = &qu.x; float* vo = &qv.x;
            #pragma unroll
            for (int c = 0; c < 4; ++c) {
                const float Axx = a[0][c], Axy = a[1][c], Ayy = a[2][c];
                const float bx = a[3][c], by = a[4][c];
                const float det = Axx * Ayy - Axy * Axy;
                const float rd  = __builtin_amdgcn_rcpf(det) * 2.0f;  // fold scale
                const bool  ok  = (det != 0.f);
                uo[c] = ok ? (Ayy * bx - Axy * by) * rd : 0.f;
                vo[c] = ok ? (Axx * by - Axy * bx) * rd : 0.f;
            }
            *reinterpret_cast<float4*>(out + (size_t)i * IW + x) = qu;
            *reinterpret_cast<float4*>(out + (size_t)IH * IW + (size_t)i * IW + x) = qv;
        }
    }

    // slide (pure register renames — each step is a distinct instantiation)
    A = B; B = C; C = D;
    if constexpr (SR + 4 <= SCAN) D = nD;
}

template<int SR, bool XE, bool YE>
__device__ __forceinline__ void lk_steps(const float* __restrict__ P,
                                         const float* __restrict__ N,
                                         float* __restrict__ out,
                                         int c0, int r0, int t, int pcb,
                                         bool lload, float keep4, bool rep4,
                                         Row& A, Row& B, Row& C, Row& D,
                                         const Row& X0, const Row& X1,
                                         const Row& X2, const Row& X3,
                                         float V[5][4]) {
    if constexpr (SR < SCAN) {
        lk_step<SR, XE, YE>(P, N, out, c0, r0, t, pcb, lload, keep4, rep4,
                            A, B, C, D, X0, X1, X2, X3, V);
        lk_steps<SR + 1, XE, YE>(P, N, out, c0, r0, t, pcb, lload, keep4, rep4,
                                 A, B, C, D, X0, X1, X2, X3, V);
    }
}

template<bool XE, bool YE>
__device__ __forceinline__ void lk_body(const float* __restrict__ P,
                                        const float* __restrict__ N,
                                        float* __restrict__ out,
                                        int c0, int r0, int t) {
    const int pcb = c0 - 8 + 4 * t;     // this lane's first tracked column
    bool  lload = true;
    float keep4 = 1.f;
    bool  rep4  = false;
    if constexpr (XE) {
        lload = (pcb >= 0) && (pcb + 3 < IW);  // full float4 in range
        keep4 = (pcb + 3 >= 0) ? 1.f : 0.f;    // lane's last col outside-left -> zero
        rep4  = (pcb + 4 >= IW);               // col-4 outside-right -> replicate
    }

    // pinned exit rows (also the first four pipeline rows)
    Row X0 = load_row<YE>(P, N, r0 - RAD + 0, pcb, lload);
    Row X1 = load_row<YE>(P, N, r0 - RAD + 1, pcb, lload);
    Row X2 = load_row<YE>(P, N, r0 - RAD + 2, pcb, lload);
    Row X3 = load_row<YE>(P, N, r0 - RAD + 3, pcb, lload);
    Row A = X0, B = X1, C = X2, D = X3;

    float V[5][4] = {};

    lk_steps<0, XE, YE>(P, N, out, c0, r0, t, pcb, lload, keep4, rep4,
                        A, B, C, D, X0, X1, X2, X3, V);
}

__global__ __launch_bounds__(NT, 4)
void lk_kernel(const float* __restrict__ Pimg, const float* __restrict__ Nimg,
               float* __restrict__ out) {
    // XCD-chunked swizzle: XCD (bid&7) owns 64 contiguous 4-row bands of one
    // strip, so vertical-halo re-reads across adjacent bands hit the local L2.
    const int bid   = blockIdx.x;
    const int xcd   = bid & 7;
    const int idx   = bid >> 3;              // 0..575
    const int strip = idx / CHUNK;           // 0..8
    const int pos   = idx % CHUNK;
    const int band  = xcd * CHUNK + pos;     // 0..511
    const int c0 = strip * SW;
    const int r0 = band * RB;
    const int t  = threadIdx.x;
    const bool xe = (strip == 0) || (strip == NSTRIP - 1);
    const bool ye = (band < 2) || (band >= NBAND - 2);
    if (!xe && !ye)      lk_body<false, false>(Pimg, Nimg, out, c0, r0, t);
    else if (xe && !ye)  lk_body<true,  false>(Pimg, Nimg, out, c0, r0, t);
    else if (!xe)        lk_body<false, true >(Pimg, Nimg, out, c0, r0, t);
    else                 lk_body<true,  true >(Pimg, Nimg, out, c0, r0, t);
}

extern "C" void kernel_launch(void* const* d_in, const int* in_sizes, int n_in,
                              void* d_out, int out_size, void* d_ws, size_t ws_size,
                              hipStream_t stream) {
    (void)in_sizes; (void)n_in; (void)d_ws; (void)ws_size; (void)out_size;
    const float* prev = (const float*)d_in[0];
    const float* nxt  = (const float*)d_in[1];
    float* out        = (float*)d_out;
    dim3 grid(NSTRIP * NBAND);               // 4608 one-wave blocks
    dim3 block(NT);
    hipLaunchKernelGGL(lk_kernel, grid, block, 0, stream, prev, nxt, out);
}